// Round 3
// baseline (1999.497 us; speedup 1.0000x reference)
//
#include <hip/hip_runtime.h>

typedef __bf16 bf16_t;
typedef __attribute__((ext_vector_type(8))) __bf16 bf16x8;
typedef __attribute__((ext_vector_type(4))) float f32x4;
typedef __attribute__((ext_vector_type(16))) float f32x16;

#define NSEQ 1024
#define SLEN 100
#define HID  512

__device__ __forceinline__ float sigf(float x) { return 1.0f / (1.0f + __expf(-x)); }
__device__ __forceinline__ float tanh_(float x) { return 1.0f - 2.0f / (__expf(2.0f * x) + 1.0f); }

__device__ __forceinline__ bf16x8 cvt8(float4 a, float4 b) {
    bf16x8 v;
    v[0] = (__bf16)a.x; v[1] = (__bf16)a.y; v[2] = (__bf16)a.z; v[3] = (__bf16)a.w;
    v[4] = (__bf16)b.x; v[5] = (__bf16)b.y; v[6] = (__bf16)b.z; v[7] = (__bf16)b.w;
    return v;
}

// ---------------------------------------------------------------------------
// Embedding GEMM: emb[t][seq][h] = sum_d x[seq][t][d] * W_e[h][d] + b_e[h]
// ---------------------------------------------------------------------------
__global__ __launch_bounds__(256)
void embed_kernel(const float* __restrict__ x, const float* __restrict__ We,
                  const float* __restrict__ be, bf16_t* __restrict__ emb)
{
    __shared__ bf16_t bsm[8 * 256 * 8];   // [q=k/8][col][8] bf16 = 32 KB
    const int bid = blockIdx.x;
    const int rowblk = bid >> 1;
    const int col0 = (bid & 1) << 8;
    const int tid = threadIdx.x;

    {
        const int col = tid;  // 0..255
        const float* src = We + (size_t)(col0 + col) * 64;
        #pragma unroll
        for (int q = 0; q < 8; ++q) {
            float4 f0 = *(const float4*)(src + q * 8);
            float4 f1 = *(const float4*)(src + q * 8 + 4);
            *(bf16x8*)&bsm[(q * 256 + col) * 8] = cvt8(f0, f1);
        }
    }
    __syncthreads();

    const int l = tid & 63, w = tid >> 6;
    const int lo = l & 15, hi = l >> 4;
    const int rowbase = rowblk * 64 + w * 16;
    const int row_a = rowbase + lo;
    const int seq = row_a & (NSEQ - 1);
    const int t = row_a >> 10;
    const float* xrow = x + ((size_t)seq * SLEN + t) * 64;

    bf16x8 a0, a1;
    {
        const float* p = xrow + hi * 8;
        a0 = cvt8(*(const float4*)p, *(const float4*)(p + 4));
        p = xrow + 32 + hi * 8;
        a1 = cvt8(*(const float4*)p, *(const float4*)(p + 4));
    }

    #pragma unroll
    for (int nf = 0; nf < 16; ++nf) {
        f32x4 acc = {0.f, 0.f, 0.f, 0.f};
        bf16x8 b0 = *(const bf16x8*)&bsm[((0 * 4 + hi) * 256 + nf * 16 + lo) * 8];
        bf16x8 b1 = *(const bf16x8*)&bsm[((1 * 4 + hi) * 256 + nf * 16 + lo) * 8];
        acc = __builtin_amdgcn_mfma_f32_16x16x32_bf16(a0, b0, acc, 0, 0, 0);
        acc = __builtin_amdgcn_mfma_f32_16x16x32_bf16(a1, b1, acc, 0, 0, 0);
        const int col = col0 + nf * 16 + lo;
        const float bias = be[col];
        #pragma unroll
        for (int r = 0; r < 4; ++r) {
            const int rr = rowbase + hi * 4 + r;
            emb[(size_t)rr * HID + col] = (bf16_t)(acc[r] + bias);
        }
    }
}

// ---------------------------------------------------------------------------
// Persistent masked-LSTM, 32x32x16 MFMA version.
// 256 blocks x 256 threads (4 waves). m = bid&7 (group of 32 blocks, 128
// seqs), jsl = bid>>3 (16 hidden units -> 64 gate cols as 2 frags of 32:
// frag0=[i|g], frag1=[f|o]). Wave = 32 seqs x 64 cols. Weights (128 KB)
// LDS-resident. Gate exchange via shfl_xor(16); cell lane-local; c in VGPRs.
// ---------------------------------------------------------------------------
__global__ __launch_bounds__(256, 1)
void lstm_kernel(const bf16_t* __restrict__ emb, const int* __restrict__ mask,
                 const float* __restrict__ Wih, const float* __restrict__ Whh,
                 const float* __restrict__ bih, const float* __restrict__ bhh,
                 const float* __restrict__ h0, const float* __restrict__ c0,
                 bf16_t* __restrict__ hbuf,        // [2][1024][512] bf16
                 unsigned int* __restrict__ cnt,   // 8 counters, stride 64 uints
                 float* __restrict__ out)
{
    extern __shared__ bf16_t wsm[];   // entry[(ks*2+halfk)*2+nf][c] of 8 bf16 = 128 KB
    const int bid = blockIdx.x;
    const int m = bid & 7;
    const int jsl = bid >> 3;
    const int jbase = jsl * 16;
    const int tid = threadIdx.x;

    // ---- stage weights: entry idx: c=idx&31, nf=(idx>>5)&1, halfk=(idx>>6)&1,
    //      kslot=idx>>7 ; gate = nf + 2*(c>>4), unit = c&15 ----
    for (int it = 0; it < 32; ++it) {
        const int idx = it * 256 + tid;
        const int c_ = idx & 31;
        const int nf = (idx >> 5) & 1;
        const int halfk = (idx >> 6) & 1;
        const int kslot = idx >> 7;
        const int gate = nf + 2 * (c_ >> 4);
        const int G = gate * 512 + jbase + (c_ & 15);
        const int k0 = kslot * 16 + halfk * 8;
        const float* src = (k0 < 512) ? (Wih + (size_t)G * 512 + k0)
                                      : (Whh + (size_t)G * 512 + (k0 - 512));
        float4 f0 = *(const float4*)src;
        float4 f1 = *(const float4*)(src + 4);
        *(bf16x8*)&wsm[(size_t)idx * 8] = cvt8(f0, f1);
    }

    const int lane = tid & 63;
    const int w = tid >> 6;           // 0..3
    const int c = lane & 31;          // col within frag / A row within wave
    const int l5 = lane >> 5;         // k-half
    const int u = c & 15;             // hidden unit within slice
    const int jg = jbase + u;
    const int seqbase = m * 128 + w * 32;
    const int seq_a = seqbase + c;    // this lane's A row

    float bs4[4];
    #pragma unroll
    for (int g = 0; g < 4; ++g) bs4[g] = bih[g * 512 + jg] + bhh[g * 512 + jg];

    float c_reg[16];
    const float c0v = c0[jg];
    #pragma unroll
    for (int r = 0; r < 16; ++r) c_reg[r] = c0v;

    // ---- init h(0) = mask0 ? emb0 : h0 for this block's 128 seqs x 16 units
    {
        const int seq0 = m * 128;
        for (int idx = tid; idx < 128 * 16; idx += 256) {
            const int s = seq0 + (idx >> 4);
            const int uu = jbase + (idx & 15);
            const int mb0 = mask[(size_t)s * SLEN];
            const float e0 = (float)emb[(size_t)s * HID + uu];
            hbuf[(size_t)s * HID + uu] = (bf16_t)(mb0 ? e0 : h0[uu]);
        }
    }
    __syncthreads();
    if (tid == 0)
        __hip_atomic_fetch_add(&cnt[m * 64], 1u, __ATOMIC_RELEASE,
                               __HIP_MEMORY_SCOPE_AGENT);

    for (int t = 0; t < SLEN; ++t) {
        // ---- prefetch (independent of h(t)) BEFORE the barrier ----
        const int mb = mask[(size_t)seq_a * SLEN + t];
        const bf16_t* eptr = emb + ((size_t)t * NSEQ + seq_a) * HID + l5 * 8;
        bf16x8 ef[8];
        #pragma unroll
        for (int ks = 0; ks < 8; ++ks)
            ef[ks] = *(const bf16x8*)(eptr + ks * 16);

        // ---- group barrier: relaxed spin, one acquire ----
        if (tid == 0) {
            const unsigned target = 32u * (unsigned)(t + 1);
            unsigned it = 0;
            while (__hip_atomic_load(&cnt[m * 64], __ATOMIC_RELAXED,
                                     __HIP_MEMORY_SCOPE_AGENT) < target &&
                   ++it < (1u << 27)) {
                __builtin_amdgcn_s_sleep(1);
            }
            (void)__hip_atomic_load(&cnt[m * 64], __ATOMIC_ACQUIRE,
                                    __HIP_MEMORY_SCOPE_AGENT);
        }
        __syncthreads();

        const bf16_t* hb_r = hbuf + (size_t)(t & 1) * (NSEQ * HID);
        bf16_t* hb_w = hbuf + (size_t)((t + 1) & 1) * (NSEQ * HID);
        const bf16_t* hptr = hb_r + (size_t)seq_a * HID + l5 * 8;

        f32x16 acc0, acc1;
        #pragma unroll
        for (int r = 0; r < 16; ++r) { acc0[r] = 0.f; acc1[r] = 0.f; }

        // K-low (x-half, select) and K-high (h-half) share the h fragment.
        #pragma unroll
        for (int ks = 0; ks < 32; ++ks) {
            const bf16x8 hF = *(const bf16x8*)(hptr + ks * 16);
            const bf16x8 eF = (ks < 8) ? ef[ks] : *(const bf16x8*)(eptr + ks * 16);
            const bf16x8 aL = mb ? eF : hF;
            const bf16_t* wb = wsm + (size_t)(((ks * 2 + l5) * 2) * 32 + c) * 8;
            const bf16_t* wbh = wsm + (size_t)((((ks + 32) * 2 + l5) * 2) * 32 + c) * 8;
            const bf16x8 b0 = *(const bf16x8*)wb;             // nf=0, K-low
            const bf16x8 b1 = *(const bf16x8*)(wb + 32 * 8);  // nf=1, K-low
            const bf16x8 b2 = *(const bf16x8*)wbh;            // nf=0, K-high
            const bf16x8 b3 = *(const bf16x8*)(wbh + 32 * 8); // nf=1, K-high
            acc0 = __builtin_amdgcn_mfma_f32_32x32x16_bf16(aL, b0, acc0, 0, 0, 0);
            acc1 = __builtin_amdgcn_mfma_f32_32x32x16_bf16(aL, b1, acc1, 0, 0, 0);
            acc0 = __builtin_amdgcn_mfma_f32_32x32x16_bf16(hF, b2, acc0, 0, 0, 0);
            acc1 = __builtin_amdgcn_mfma_f32_32x32x16_bf16(hF, b3, acc1, 0, 0, 0);
        }

        // ---- gate exchange + lane-local cell update ----
        // frag0=[i|g], frag1=[f|o]; partner lane = lane^16 (same l5 half).
        #pragma unroll
        for (int r = 0; r < 16; ++r) {
            const float p0 = __shfl_xor(acc0[r], 16, 64);
            const float p1 = __shfl_xor(acc1[r], 16, 64);
            float iv, fv, gv, ov;
            if (c < 16) { iv = acc0[r]; fv = acc1[r]; gv = p0; ov = p1; }
            else        { iv = p0;      fv = p1;      gv = acc0[r]; ov = acc1[r]; }
            iv += bs4[0]; fv += bs4[1]; gv += bs4[2]; ov += bs4[3];
            const float cn = sigf(fv) * c_reg[r] + sigf(iv) * tanh_(gv);
            c_reg[r] = cn;
            const float hv = sigf(ov) * tanh_(cn);
            const int s = seqbase + (r & 3) + 8 * (r >> 2) + 4 * l5;
            if (c < 16) {
                hb_w[(size_t)s * HID + jg] = (bf16_t)hv;
                if (t == SLEN - 1) out[(size_t)s * HID + jg] = hv;
            }
        }
        __syncthreads();
        if (tid == 0)
            __hip_atomic_fetch_add(&cnt[m * 64], 1u, __ATOMIC_RELEASE,
                                   __HIP_MEMORY_SCOPE_AGENT);
    }
}

// ---------------------------------------------------------------------------
extern "C" void kernel_launch(void* const* d_in, const int* in_sizes, int n_in,
                              void* d_out, int out_size, void* d_ws, size_t ws_size,
                              hipStream_t stream)
{
    const float* x    = (const float*)d_in[0];
    const int*   mask = (const int*)d_in[1];
    const float* We   = (const float*)d_in[2];
    const float* be   = (const float*)d_in[3];
    const float* Wih  = (const float*)d_in[4];
    const float* Whh  = (const float*)d_in[5];
    const float* bih  = (const float*)d_in[6];
    const float* bhh  = (const float*)d_in[7];
    const float* h0   = (const float*)d_in[8];
    const float* c0   = (const float*)d_in[9];
    float* out = (float*)d_out;

    unsigned char* ws = (unsigned char*)d_ws;
    unsigned int* cnt = (unsigned int*)ws;                       // 4 KB
    bf16_t* hbuf = (bf16_t*)(ws + 4096);                         // 2 MB
    bf16_t* emb  = (bf16_t*)(ws + 4096 + (size_t)2 * NSEQ * HID * 2);  // ~100 MB

    hipMemsetAsync(cnt, 0, 4096, stream);

    embed_kernel<<<3200, 256, 0, stream>>>(x, We, be, emb);

    hipFuncSetAttribute(reinterpret_cast<const void*>(lstm_kernel),
                        hipFuncAttributeMaxDynamicSharedMemorySize, 131072);
    lstm_kernel<<<256, 256, 131072, stream>>>(emb, mask, Wih, Whh, bih, bhh,
                                              h0, c0, hbuf, cnt, out);
}